// Round 12
// baseline (2568.815 us; speedup 1.0000x reference)
//
#include <hip/hip_runtime.h>

// LSTM 2-layer fused persistent kernel — MFMA fp16 2-term split, fp32 I/O.
// R12 change vs R11: 4-wave blocks (256 thr). VGPR grant law 65536/threads
// (512->128, 1024->64, proven x2 each) predicts 256 thr -> 256 VGPR. Each
// wave owns 8 M-tiles (Ahi 128 VGPR + acc 64 + temps ~225 < 256). Same
// total MFMA work, but per-CU LDS B-read traffic HALVES (R11 limiter:
// 8 waves x 8 ds_read_b128 of the SAME h vector ~850cyc/step on the shared
// LDS pipe) and the barrier narrows to 4 waves. Epilogue: 2 units/lane.
// Also: sigmoid 0.5-prescale folded into packed weights & bias (g-gate rows
// unscaled); sched_barriers removed (reg headroom).
// Gate-major ownership: wave w owns {i,f,g,o} x units [32w,32w+32);
// tile t8 = gate*2 + t2, row = (t8>>1)*128 + w*32 + (t8&1)*16 + (lane&15).
// c-update wave-local via __shfl; h ping-pong (L1); 1 barrier/step.
// Fragment maps (m89-verified): A[row=lane&15, k=(lane>>4)*8+j],
// B[k=(lane>>4)*8+j, col=lane&15]; B column-replicated -> all lanes valid.
// d_ws requirement: 458,752 B.

typedef __attribute__((ext_vector_type(4))) float f32x4;
typedef _Float16 f16x8 __attribute__((ext_vector_type(8)));

#define NB   256
#define TSEQ 1024
#define II   64
#define HH   128
#define G4   512
#define TC   16
#define NCH  (TSEQ/TC)
#define SCL  0.0009765625f   // 2^-10
#define SCLI 1024.f          // 2^10

// d_ws frag regions (16B units). idx = region + ((w*8+t8)*NKS+s)*64 + lane.
#define F_WHH0  0
#define F_WHH1  8192
#define F_WIH1  16384
#define F_WIH0  24576
#define F_TOTAL 28672   // *16B = 458,752 B

#define KEEP4I(v) asm volatile("" : "+v"((v).x), "+v"((v).y), "+v"((v).z), "+v"((v).w))

__device__ __forceinline__ float tanh_f(float x){
    float ax = fabsf(x);
    float e  = __expf(2.f*ax);
    float t  = 1.f - 2.f*__builtin_amdgcn_rcpf(e + 1.f);
    return copysignf(t, x);
}
__device__ __forceinline__ f32x4 mfma16(int4 a, f16x8 b, f32x4 c){
    return __builtin_amdgcn_mfma_f32_16x16x32_f16(
        __builtin_bit_cast(f16x8, a), b, c, 0, 0, 0);
}
__device__ __forceinline__ f16x8 ldb(const _Float16* p){
    return __builtin_bit_cast(f16x8, *(const int4*)p);
}

// ---------------- pack kernel: fp32 weights -> fp16 A-fragments ------------
// row = (t8>>1)*128 + w*32 + (t8&1)*16 + (lane&15); k = s*32 + (lane>>4)*8+j.
// Non-g gate rows (gate != 2) pre-scaled by 0.5 (sigmoid via tanh(x/2)).
__global__ void pack_w(const float* __restrict__ Wih0, const float* __restrict__ Whh0,
                       const float* __restrict__ Wih1, const float* __restrict__ Whh1,
                       int4* __restrict__ ws)
{
    int fid = blockIdx.x * 256 + threadIdx.x;
    if (fid >= F_TOTAL) return;
    const float* src; int nks; int rb;
    if (fid < F_WHH1)      { src = Whh0; nks = 4; rb = fid; }
    else if (fid < F_WIH1) { src = Whh1; nks = 4; rb = fid - F_WHH1; }
    else if (fid < F_WIH0) { src = Wih1; nks = 4; rb = fid - F_WIH1; }
    else                   { src = Wih0; nks = 2; rb = fid - F_WIH0; }
    int lane = rb & 63;
    int rem  = rb >> 6;
    int s    = rem % nks;
    int t8   = (rem / nks) & 7;
    int w    = rem / (nks * 8);
    int gate = t8 >> 1;
    int row  = gate * 128 + w * 32 + (t8 & 1) * 16 + (lane & 15);
    float scale = (gate == 2) ? 1.f : 0.5f;
    int K    = nks * 32;
    int k0   = s * 32 + (lane >> 4) * 8;
    const float* p = src + (size_t)row * K + k0;
    unsigned short us[8];
    #pragma unroll
    for (int j = 0; j < 8; ++j)
        us[j] = __builtin_bit_cast(unsigned short, (_Float16)(p[j] * scale));
    int4 o;
    o.x = (int)((unsigned)us[0] | ((unsigned)us[1] << 16));
    o.y = (int)((unsigned)us[2] | ((unsigned)us[3] << 16));
    o.z = (int)((unsigned)us[4] | ((unsigned)us[5] << 16));
    o.w = (int)((unsigned)us[6] | ((unsigned)us[7] << 16));
    ws[fid] = o;
}

// ---------------- serial 16-step recurrence (one layer) --------------------
template<int LAYER>
__device__ __forceinline__ void serial16(
    int w, int lane, int lk, int lm,
    const int4* __restrict__ ws,
    float (&xp)[TC][G4],
    _Float16 (&hist_hi)[TC+1][136], _Float16 (&hist_lo)[TC+1][136],
    _Float16 (&h1_hi)[2][HH], _Float16 (&h1_lo)[2][HH], float* h1f,
    float& cA, float& cB)
{
    const int F = LAYER ? F_WHH1 : F_WHH0;
    int4 Ahi[8][4];
    #pragma unroll
    for (int t8 = 0; t8 < 8; ++t8)
        #pragma unroll
        for (int s = 0; s < 4; ++s)
            Ahi[t8][s] = ws[F + (((w*8 + t8)*4 + s) << 6) + lane];
    #pragma unroll
    for (int t8 = 0; t8 < 8; ++t8)
        #pragma unroll
        for (int s = 0; s < 4; ++s) KEEP4I(Ahi[t8][s]);

    const int gsel = lm >> 2;                    // this lane's gate (0..3)
    const int usel = lm & 3;
    const int uA   = w*32 + lk*4 + usel;         // unit A (t2=0)
    const int uB   = uA + 16;                    // unit B (t2=1)
    const int xprA = gsel*128 + w*32 + lk*4 + usel;
    const int base = lane & 0x33;                // zero gate bits [3:2]
    const bool writer = (gsel == 0);
    const bool is_g   = (gsel == 2);

    #pragma unroll 1
    for (int t = 0; t < TC; ++t){
        const _Float16* hhp = LAYER ? &h1_hi[t&1][0] : &hist_hi[t][0];
        const _Float16* hlp = LAYER ? &h1_lo[t&1][0] : &hist_lo[t][0];
        float xpvA = xp[t][xprA];
        float xpvB = xp[t][xprA + 16];
        f32x4 acc[8], accL[8];
        #pragma unroll
        for (int i = 0; i < 8; ++i){
            acc[i]  = (f32x4){0.f,0.f,0.f,0.f};
            accL[i] = (f32x4){0.f,0.f,0.f,0.f};
        }
        #pragma unroll
        for (int s = 0; s < 4; ++s){
            f16x8 bh = ldb(&hhp[s*32 + lk*8]);
            f16x8 bl = ldb(&hlp[s*32 + lk*8]);
            #pragma unroll
            for (int t8 = 0; t8 < 8; ++t8) acc[t8]  = mfma16(Ahi[t8][s], bh, acc[t8]);
            #pragma unroll
            for (int t8 = 0; t8 < 8; ++t8) accL[t8] = mfma16(Ahi[t8][s], bl, accL[t8]);
        }
        f32x4 cmb[8];
        #pragma unroll
        for (int i = 0; i < 8; ++i) cmb[i] = acc[i] + accL[i]*SCL;

        // two units per lane: t2=0 (tiles 0,2,4,6) and t2=1 (tiles 1,3,5,7)
        float yA, yB;
        {
            f32x4 sA = (gsel & 1) ? cmb[2] : cmb[0];
            f32x4 sB = (gsel & 1) ? cmb[6] : cmb[4];
            f32x4 sC = (gsel & 2) ? sB : sA;
            float v01 = (usel & 1) ? sC[1] : sC[0];
            float v23 = (usel & 1) ? sC[3] : sC[2];
            float v   = (usel & 2) ? v23 : v01;
            float z   = tanh_f(v + xpvA);        // pre already 0.5-scaled for sigm
            yA = is_g ? z : 0.5f*z + 0.5f;
        }
        {
            f32x4 sA = (gsel & 1) ? cmb[3] : cmb[1];
            f32x4 sB = (gsel & 1) ? cmb[7] : cmb[5];
            f32x4 sC = (gsel & 2) ? sB : sA;
            float v01 = (usel & 1) ? sC[1] : sC[0];
            float v23 = (usel & 1) ? sC[3] : sC[2];
            float v   = (usel & 2) ? v23 : v01;
            float z   = tanh_f(v + xpvB);
            yB = is_g ? z : 0.5f*z + 0.5f;
        }
        // wave-local gate gathers
        float giA = __shfl(yA, base),      giB = __shfl(yB, base);
        float gfA = __shfl(yA, base | 4),  gfB = __shfl(yB, base | 4);
        float ggA = __shfl(yA, base | 8),  ggB = __shfl(yB, base | 8);
        float goA = __shfl(yA, base | 12), goB = __shfl(yB, base | 12);
        cA = gfA*cA + giA*ggA;
        cB = gfB*cB + giB*ggB;
        float hA = goA * tanh_f(cA);
        float hB = goB * tanh_f(cB);
        _Float16 hfA = (_Float16)hA, hfB = (_Float16)hB;
        _Float16 hlA = (_Float16)((hA - (float)hfA) * SCLI);
        _Float16 hlB = (_Float16)((hB - (float)hfB) * SCLI);
        if (writer){
            if (LAYER){
                h1_hi[(t+1)&1][uA] = hfA; h1_lo[(t+1)&1][uA] = hlA; h1f[uA] = hA;
                h1_hi[(t+1)&1][uB] = hfB; h1_lo[(t+1)&1][uB] = hlB; h1f[uB] = hB;
            } else {
                hist_hi[t+1][uA] = hfA; hist_lo[t+1][uA] = hlA;
                hist_hi[t+1][uB] = hfB; hist_lo[t+1][uB] = hlB;
            }
        }
        __syncthreads();   // single barrier per step
    }
}

// ---------------- main persistent kernel -----------------------------------
__global__ __launch_bounds__(256, 1)
void lstm_mfma(const float* __restrict__ x,
               const float* __restrict__ bih0, const float* __restrict__ bhh0,
               const float* __restrict__ bih1, const float* __restrict__ bhh1,
               const float* __restrict__ Wlin, const float* __restrict__ blin,
               const int4* __restrict__ ws,
               float* __restrict__ out)
{
    const int b    = blockIdx.x;
    const int tid  = threadIdx.x;
    const int lane = tid & 63;
    const int w    = tid >> 6;          // wave 0..3
    const int lm   = lane & 15;
    const int lk   = lane >> 4;

    __shared__ __align__(16) float    xp[TC][G4];            // 32,768 B
    __shared__ __align__(16) _Float16 hist_hi[TC+1][136];    //  4,624 B
    __shared__ __align__(16) _Float16 hist_lo[TC+1][136];    //  4,624 B
    __shared__ __align__(16) _Float16 xc_hi[TC][72];         //  2,304 B
    __shared__ __align__(16) _Float16 xc_lo[TC][72];         //  2,304 B
    __shared__ __align__(16) _Float16 h1_hi[2][HH];          //    512 B
    __shared__ __align__(16) _Float16 h1_lo[2][HH];          //    512 B
    __shared__ __align__(16) float    h1f[HH];               //    512 B
    __shared__ __align__(16) float    bias[2][G4];           //  4,096 B
    // ~52 KB

    {   // bias with sigmoid 0.5-prescale (gate = row>>7; g gate = 2)
        int r0 = tid, r1 = tid + 256;
        float s0 = ((r0 >> 7) == 2) ? 1.f : 0.5f;
        float s1 = ((r1 >> 7) == 2) ? 1.f : 0.5f;
        bias[0][r0] = (bih0[r0] + bhh0[r0]) * s0;
        bias[0][r1] = (bih0[r1] + bhh0[r1]) * s1;
        bias[1][r0] = (bih1[r0] + bhh1[r0]) * s0;
        bias[1][r1] = (bih1[r1] + bhh1[r1]) * s1;
    }
    if (tid < HH){ hist_hi[0][tid] = (_Float16)0.f; hist_lo[0][tid] = (_Float16)0.f;
                   h1_hi[0][tid] = (_Float16)0.f; h1_lo[0][tid] = (_Float16)0.f;
                   h1f[tid] = 0.f; }
    float c0A = 0.f, c0B = 0.f, c1A = 0.f, c1B = 0.f;
    const float* xb = x + (size_t)b * TSEQ * II;
    __syncthreads();

    #pragma unroll 1
    for (int ch = 0; ch < NCH; ++ch){
        // ---- A: stage x chunk as fp16 hi + scaled lo; carry h0 ----
        #pragma unroll
        for (int j = 0; j < 4; ++j){
            int i = tid + 256*j;
            float v = xb[(size_t)ch*TC*II + i];
            _Float16 a = (_Float16)v;
            xc_hi[i>>6][i&63] = a;
            xc_lo[i>>6][i&63] = (_Float16)((v - (float)a)*SCLI);
        }
        if (ch > 0 && tid < HH){
            hist_hi[0][tid] = hist_hi[TC][tid];
            hist_lo[0][tid] = hist_lo[TC][tid];
        }
        __syncthreads();

        // ---- B: proj xp0 (K=64, B = xc fp16 pairs) ----
        {
            f32x4 acc[8], accL[8];
            #pragma unroll
            for (int i = 0; i < 8; ++i){
                acc[i]  = (f32x4){0.f,0.f,0.f,0.f};
                accL[i] = (f32x4){0.f,0.f,0.f,0.f};
            }
            #pragma unroll
            for (int s = 0; s < 2; ++s){
                f16x8 bh = ldb(&xc_hi[lm][s*32 + lk*8]);
                f16x8 bl = ldb(&xc_lo[lm][s*32 + lk*8]);
                int4 ah[8];
                #pragma unroll
                for (int t8 = 0; t8 < 8; ++t8)
                    ah[t8] = ws[F_WIH0 + (((w*8 + t8)*2 + s) << 6) + lane];
                #pragma unroll
                for (int t8 = 0; t8 < 8; ++t8) acc[t8]  = mfma16(ah[t8], bh, acc[t8]);
                #pragma unroll
                for (int t8 = 0; t8 < 8; ++t8) accL[t8] = mfma16(ah[t8], bl, accL[t8]);
            }
            #pragma unroll
            for (int t8 = 0; t8 < 8; ++t8){
                int rowb = (t8>>1)*128 + w*32 + (t8&1)*16 + lk*4;
                f32x4 cmb = acc[t8] + accL[t8]*SCL;
                *(f32x4*)&xp[lm][rowb] = cmb + *(const f32x4*)&bias[0][rowb];
            }
        }
        __syncthreads();

        // ---- C: layer0 serial 16 steps ----
        serial16<0>(w, lane, lk, lm, ws, xp, hist_hi, hist_lo,
                    h1_hi, h1_lo, h1f, c0A, c0B);

        // ---- D: proj xp1 (K=128, B = hist fp16 pairs) ----
        {
            f32x4 acc[8], accL[8];
            #pragma unroll
            for (int i = 0; i < 8; ++i){
                acc[i]  = (f32x4){0.f,0.f,0.f,0.f};
                accL[i] = (f32x4){0.f,0.f,0.f,0.f};
            }
            #pragma unroll
            for (int s = 0; s < 4; ++s){
                f16x8 bh = ldb(&hist_hi[lm + 1][s*32 + lk*8]);
                f16x8 bl = ldb(&hist_lo[lm + 1][s*32 + lk*8]);
                int4 ah[8];
                #pragma unroll
                for (int t8 = 0; t8 < 8; ++t8)
                    ah[t8] = ws[F_WIH1 + (((w*8 + t8)*4 + s) << 6) + lane];
                #pragma unroll
                for (int t8 = 0; t8 < 8; ++t8) acc[t8]  = mfma16(ah[t8], bh, acc[t8]);
                #pragma unroll
                for (int t8 = 0; t8 < 8; ++t8) accL[t8] = mfma16(ah[t8], bl, accL[t8]);
            }
            #pragma unroll
            for (int t8 = 0; t8 < 8; ++t8){
                int rowb = (t8>>1)*128 + w*32 + (t8&1)*16 + lk*4;
                f32x4 cmb = acc[t8] + accL[t8]*SCL;
                *(f32x4*)&xp[lm][rowb] = cmb + *(const f32x4*)&bias[1][rowb];
            }
        }
        __syncthreads();

        // ---- E: layer1 serial 16 steps ----
        serial16<1>(w, lane, lk, lm, ws, xp, hist_hi, hist_lo,
                    h1_hi, h1_lo, h1f, c1A, c1B);
    }

    // ---- final linear: out[b] = h1 . Wlin[0,:] + blin ----
    if (tid < 64){
        float s = h1f[tid]*Wlin[tid] + h1f[tid+64]*Wlin[tid+64];
        #pragma unroll
        for (int off = 32; off; off >>= 1) s += __shfl_down(s, off);
        if (tid == 0) out[b] = s + blin[0];
    }
}

extern "C" void kernel_launch(void* const* d_in, const int* in_sizes, int n_in,
                              void* d_out, int out_size, void* d_ws, size_t ws_size,
                              hipStream_t stream)
{
    const float* x    = (const float*)d_in[0];
    const float* Wih0 = (const float*)d_in[1];
    const float* Whh0 = (const float*)d_in[2];
    const float* bih0 = (const float*)d_in[3];
    const float* bhh0 = (const float*)d_in[4];
    const float* Wih1 = (const float*)d_in[5];
    const float* Whh1 = (const float*)d_in[6];
    const float* bih1 = (const float*)d_in[7];
    const float* bhh1 = (const float*)d_in[8];
    const float* Wlin = (const float*)d_in[9];
    const float* blin = (const float*)d_in[10];
    int4* ws = (int4*)d_ws;   // requires ws_size >= 458,752 B

    hipLaunchKernelGGL(pack_w, dim3(F_TOTAL/256), dim3(256), 0, stream,
                       Wih0, Whh0, Wih1, Whh1, ws);
    hipLaunchKernelGGL(lstm_mfma, dim3(NB), dim3(256), 0, stream,
                       x, bih0, bhh0, bih1, bhh1, Wlin, blin, ws, (float*)d_out);
}

// Round 13
// 1550.171 us; speedup vs baseline: 1.6571x; 1.6571x over previous
//
#include <hip/hip_runtime.h>

// LSTM 2-layer fused persistent kernel — MFMA fp16 2-term split, fp32 I/O.
// R13 change vs R11 (the 2,131us anchor; R12's 256-thr experiment regressed
// to 1 wave/SIMD and is abandoned): N-PACKED hi/lo terms. B's 16 columns
// were all h_hi replicas (15/16 of each MFMA wasted + separate accL pass).
// Now even cols = h_hi, odd cols = h_lo (per-lane address select, 2-address
// broadcast = free): one MFMA computes both terms -> serial MFMA 32->16 and
// ds_read_b128 8->4 per wave per step. Combine via one shfl_xor(1): lane lm
// extracts acc[gsel][usel] (own) + acc[gsel][usel^1] (sent to partner);
// pre = odd ? recv + SCL*own : own + SCL*recv.  Everything else = R11.
// Config: 256 blocks x 512 thr (8 waves, 2/SIMD), __launch_bounds__(512,2)
// = the proven 128-VGPR no-spill regime (grant law 65536/threads, 4x proven).
// Gate-major ownership: wave w owns {i,f,g,o} x units [16w,16w+16);
// c-update wave-local via 4 __shfl; h ping-pong; 1 barrier/step.
// Fragment maps (m89-verified): A[row=lane&15, k=(lane>>4)*8+j],
// B[k=(lane>>4)*8+j, col=lane&15], D[col=lane&15, row=(lane>>4)*4+reg].
// d_ws requirement: 458,752 B.

typedef __attribute__((ext_vector_type(4))) float f32x4;
typedef _Float16 f16x8 __attribute__((ext_vector_type(8)));

#define NB   256
#define TSEQ 1024
#define II   64
#define HH   128
#define G4   512
#define TC   16
#define NCH  (TSEQ/TC)
#define SCL  0.0009765625f   // 2^-10
#define SCLI 1024.f          // 2^10

// d_ws frag regions (16B units). idx = region + ((w*4+t4)*NKS+s)*64 + lane.
#define F_WHH0  0
#define F_WHH1  8192
#define F_WIH1  16384
#define F_WIH0  24576
#define F_TOTAL 28672   // *16B = 458,752 B

#define KEEP4I(v) asm volatile("" : "+v"((v).x), "+v"((v).y), "+v"((v).z), "+v"((v).w))

__device__ __forceinline__ float tanh_f(float x){
    float ax = fabsf(x);
    float e  = __expf(2.f*ax);
    float t  = 1.f - 2.f*__builtin_amdgcn_rcpf(e + 1.f);
    return copysignf(t, x);
}
__device__ __forceinline__ f32x4 mfma16(int4 a, f16x8 b, f32x4 c){
    return __builtin_amdgcn_mfma_f32_16x16x32_f16(
        __builtin_bit_cast(f16x8, a), b, c, 0, 0, 0);
}
__device__ __forceinline__ f16x8 ldb(const _Float16* p){
    return __builtin_bit_cast(f16x8, *(const int4*)p);
}

// ---------------- pack kernel: fp32 weights -> fp16 A-fragments ------------
// Gate-major row map: fragment (w, t4, s, lane) holds
// row = t4*128 + w*16 + (lane&15), k = s*32 + (lane>>4)*8 + j.
__global__ void pack_w(const float* __restrict__ Wih0, const float* __restrict__ Whh0,
                       const float* __restrict__ Wih1, const float* __restrict__ Whh1,
                       int4* __restrict__ ws)
{
    int fid = blockIdx.x * 256 + threadIdx.x;
    if (fid >= F_TOTAL) return;
    const float* src; int nks; int rb;
    if (fid < F_WHH1)      { src = Whh0; nks = 4; rb = fid; }
    else if (fid < F_WIH1) { src = Whh1; nks = 4; rb = fid - F_WHH1; }
    else if (fid < F_WIH0) { src = Wih1; nks = 4; rb = fid - F_WIH1; }
    else                   { src = Wih0; nks = 2; rb = fid - F_WIH0; }
    int lane = rb & 63;
    int rem  = rb >> 6;
    int s    = rem % nks;
    int t    = (rem / nks) & 3;
    int w    = rem / (nks * 4);
    int row  = t * 128 + w * 16 + (lane & 15);   // gate-major
    int K    = nks * 32;
    int k0   = s * 32 + (lane >> 4) * 8;
    const float* p = src + (size_t)row * K + k0;
    unsigned short us[8];
    #pragma unroll
    for (int j = 0; j < 8; ++j)
        us[j] = __builtin_bit_cast(unsigned short, (_Float16)p[j]);  // RNE
    int4 o;
    o.x = (int)((unsigned)us[0] | ((unsigned)us[1] << 16));
    o.y = (int)((unsigned)us[2] | ((unsigned)us[3] << 16));
    o.z = (int)((unsigned)us[4] | ((unsigned)us[5] << 16));
    o.w = (int)((unsigned)us[6] | ((unsigned)us[7] << 16));
    ws[fid] = o;
}

// ---------------- serial 16-step recurrence (one layer) --------------------
template<int LAYER>
__device__ __forceinline__ void serial16(
    int w, int lane, int lk, int lm,
    const int4* __restrict__ ws,
    float (&xp)[TC][G4],
    _Float16 (&hist_hi)[TC+1][136], _Float16 (&hist_lo)[TC+1][136],
    _Float16 (&h1_hi)[2][HH], _Float16 (&h1_lo)[2][HH], float* h1f,
    float& c)
{
    const int F = LAYER ? F_WHH1 : F_WHH0;
    int4 Ahi[4][4];
    #pragma unroll
    for (int t4 = 0; t4 < 4; ++t4)
        #pragma unroll
        for (int s = 0; s < 4; ++s)
            Ahi[t4][s] = ws[F + (((w*4 + t4)*4 + s) << 6) + lane];
    #pragma unroll
    for (int t4 = 0; t4 < 4; ++t4)
        #pragma unroll
        for (int s = 0; s < 4; ++s) KEEP4I(Ahi[t4][s]);

    const int gsel = lm >> 2;                    // this lane's gate (0..3)
    const int usel = lm & 3;
    const int u    = w*16 + lk*4 + usel;         // unit owned
    const int xpr  = gsel*128 + w*16 + lk*4 + usel;
    const int base = lane & 0x33;                // zero gate bits [3:2]
    const bool writer = (gsel == 0);
    const bool is_g   = (gsel == 2);
    const bool odd    = (lane & 1);              // odd col = lo-term column

    #pragma unroll 1
    for (int t = 0; t < TC; ++t){
        const _Float16* hhp = LAYER ? &h1_hi[t&1][0] : &hist_hi[t][0];
        const _Float16* hlp = LAYER ? &h1_lo[t&1][0] : &hist_lo[t][0];
        const _Float16* bp  = odd ? hlp : hhp;   // per-lane addr select (no divergence)
        float xpv = xp[t][xpr];
        f32x4 acc[4];
        #pragma unroll
        for (int t4 = 0; t4 < 4; ++t4) acc[t4] = (f32x4){0.f,0.f,0.f,0.f};
        #pragma unroll
        for (int s = 0; s < 4; ++s){
            f16x8 bv = ldb(&bp[s*32 + lk*8]);    // even lanes: hi, odd lanes: lo
            #pragma unroll
            for (int t4 = 0; t4 < 4; ++t4) acc[t4] = mfma16(Ahi[t4][s], bv, acc[t4]);
        }
        // extract own (reg=usel) and partner-row (reg=usel^1) values of tile gsel
        f32x4 ps;
        {
            f32x4 p01 = (gsel & 1) ? acc[1] : acc[0];
            f32x4 p23 = (gsel & 1) ? acc[3] : acc[2];
            ps = (gsel & 2) ? p23 : p01;
        }
        float own, oth;
        {
            float a01 = (usel & 1) ? ps[1] : ps[0];
            float a23 = (usel & 1) ? ps[3] : ps[2];
            own = (usel & 2) ? a23 : a01;
            float b01 = (usel & 1) ? ps[0] : ps[1];
            float b23 = (usel & 1) ? ps[2] : ps[3];
            oth = (usel & 2) ? b23 : b01;
        }
        float recv = __shfl_xor(oth, 1);         // partner's opposite-term of MY row
        float pre  = (odd ? (recv + SCL*own) : (own + SCL*recv)) + xpv;
        float z    = tanh_f(is_g ? pre : 0.5f*pre);
        float y    = is_g ? z : 0.5f*z + 0.5f;   // sigm via tanh
        // wave-local gate gather: unit u's i,f,g,o sit 4 lanes apart
        float gi = __shfl(y, base);
        float gf = __shfl(y, base | 4);
        float gg = __shfl(y, base | 8);
        float go = __shfl(y, base | 12);
        c = gf*c + gi*gg;
        float h = go * tanh_f(c);
        _Float16 hf = (_Float16)h;
        _Float16 hl = (_Float16)((h - (float)hf) * SCLI);
        if (writer){
            if (LAYER){
                h1_hi[(t+1)&1][u] = hf; h1_lo[(t+1)&1][u] = hl; h1f[u] = h;
            } else {
                hist_hi[t+1][u] = hf; hist_lo[t+1][u] = hl;
            }
        }
        __syncthreads();   // single barrier per step
    }
}

// ---------------- main persistent kernel -----------------------------------
__global__ __launch_bounds__(512, 2)
void lstm_mfma(const float* __restrict__ x,
               const float* __restrict__ bih0, const float* __restrict__ bhh0,
               const float* __restrict__ bih1, const float* __restrict__ bhh1,
               const float* __restrict__ Wlin, const float* __restrict__ blin,
               const int4* __restrict__ ws,
               float* __restrict__ out)
{
    const int b    = blockIdx.x;
    const int tid  = threadIdx.x;
    const int lane = tid & 63;
    const int w    = tid >> 6;
    const int lm   = lane & 15;
    const int lk   = lane >> 4;

    __shared__ __align__(16) float    xp[TC][G4];            // 32,768 B
    __shared__ __align__(16) _Float16 hist_hi[TC+1][136];    //  4,624 B
    __shared__ __align__(16) _Float16 hist_lo[TC+1][136];    //  4,624 B
    __shared__ __align__(16) _Float16 xc_hi[TC][72];         //  2,304 B
    __shared__ __align__(16) _Float16 xc_lo[TC][72];         //  2,304 B
    __shared__ __align__(16) _Float16 h1_hi[2][HH];          //    512 B
    __shared__ __align__(16) _Float16 h1_lo[2][HH];          //    512 B
    __shared__ __align__(16) float    h1f[HH];               //    512 B
    __shared__ __align__(16) float    bias[2][G4];           //  4,096 B
    // ~52 KB

    bias[0][tid] = bih0[tid] + bhh0[tid];
    bias[1][tid] = bih1[tid] + bhh1[tid];
    if (tid < HH){ hist_hi[0][tid] = (_Float16)0.f; hist_lo[0][tid] = (_Float16)0.f;
                   h1_hi[0][tid] = (_Float16)0.f; h1_lo[0][tid] = (_Float16)0.f;
                   h1f[tid] = 0.f; }
    float c0 = 0.f, c1 = 0.f;
    const float* xb = x + (size_t)b * TSEQ * II;
    __syncthreads();

    #pragma unroll 1
    for (int ch = 0; ch < NCH; ++ch){
        // ---- A: stage x chunk as fp16 hi + scaled lo; carry h0 ----
        {
            int i0 = tid, i1 = tid + 512;
            float v0 = xb[(size_t)ch*TC*II + i0];
            float v1 = xb[(size_t)ch*TC*II + i1];
            _Float16 a0 = (_Float16)v0, a1 = (_Float16)v1;
            xc_hi[i0>>6][i0&63] = a0; xc_lo[i0>>6][i0&63] = (_Float16)((v0 - (float)a0)*SCLI);
            xc_hi[i1>>6][i1&63] = a1; xc_lo[i1>>6][i1&63] = (_Float16)((v1 - (float)a1)*SCLI);
        }
        if (ch > 0 && tid < HH){
            hist_hi[0][tid] = hist_hi[TC][tid];
            hist_lo[0][tid] = hist_lo[TC][tid];
        }
        __syncthreads();

        // ---- B: proj xp0 (K=64, B = xc fp16 pairs, 16 timestep-cols) ----
        {
            f32x4 acc[4], accL[4];
            #pragma unroll
            for (int t4 = 0; t4 < 4; ++t4){
                acc[t4]  = (f32x4){0.f,0.f,0.f,0.f};
                accL[t4] = (f32x4){0.f,0.f,0.f,0.f};
            }
            #pragma unroll
            for (int s = 0; s < 2; ++s){
                f16x8 bh = ldb(&xc_hi[lm][s*32 + lk*8]);
                f16x8 bl = ldb(&xc_lo[lm][s*32 + lk*8]);
                int4 ah[4];
                #pragma unroll
                for (int t4 = 0; t4 < 4; ++t4)
                    ah[t4] = ws[F_WIH0 + (((w*4 + t4)*2 + s) << 6) + lane];
                #pragma unroll
                for (int t4 = 0; t4 < 4; ++t4) acc[t4]  = mfma16(ah[t4], bh, acc[t4]);
                #pragma unroll
                for (int t4 = 0; t4 < 4; ++t4) accL[t4] = mfma16(ah[t4], bl, accL[t4]);
            }
            #pragma unroll
            for (int t4 = 0; t4 < 4; ++t4){
                int rowb = t4*128 + w*16 + lk*4;      // gate-major row base
                f32x4 cmb = acc[t4] + accL[t4]*SCL;
                *(f32x4*)&xp[lm][rowb] = cmb + *(const f32x4*)&bias[0][rowb];
            }
        }
        __syncthreads();

        // ---- C: layer0 serial 16 steps ----
        serial16<0>(w, lane, lk, lm, ws, xp, hist_hi, hist_lo,
                    h1_hi, h1_lo, h1f, c0);

        // ---- D: proj xp1 (K=128, B = hist fp16 pairs) ----
        {
            f32x4 acc[4], accL[4];
            #pragma unroll
            for (int t4 = 0; t4 < 4; ++t4){
                acc[t4]  = (f32x4){0.f,0.f,0.f,0.f};
                accL[t4] = (f32x4){0.f,0.f,0.f,0.f};
            }
            #pragma unroll
            for (int s = 0; s < 4; ++s){
                f16x8 bh = ldb(&hist_hi[lm + 1][s*32 + lk*8]);
                f16x8 bl = ldb(&hist_lo[lm + 1][s*32 + lk*8]);
                int4 ah[4];
                #pragma unroll
                for (int t4 = 0; t4 < 4; ++t4)
                    ah[t4] = ws[F_WIH1 + (((w*4 + t4)*4 + s) << 6) + lane];
                #pragma unroll
                for (int t4 = 0; t4 < 4; ++t4) acc[t4]  = mfma16(ah[t4], bh, acc[t4]);
                #pragma unroll
                for (int t4 = 0; t4 < 4; ++t4) accL[t4] = mfma16(ah[t4], bl, accL[t4]);
                if (s == 1) __builtin_amdgcn_sched_barrier(0);
            }
            #pragma unroll
            for (int t4 = 0; t4 < 4; ++t4){
                int rowb = t4*128 + w*16 + lk*4;
                f32x4 cmb = acc[t4] + accL[t4]*SCL;
                *(f32x4*)&xp[lm][rowb] = cmb + *(const f32x4*)&bias[1][rowb];
            }
        }
        __syncthreads();

        // ---- E: layer1 serial 16 steps ----
        serial16<1>(w, lane, lk, lm, ws, xp, hist_hi, hist_lo,
                    h1_hi, h1_lo, h1f, c1);
    }

    // ---- final linear: out[b] = h1 . Wlin[0,:] + blin ----
    if (tid < 64){
        float s = h1f[tid]*Wlin[tid] + h1f[tid+64]*Wlin[tid+64];
        #pragma unroll
        for (int off = 32; off; off >>= 1) s += __shfl_down(s, off);
        if (tid == 0) out[b] = s + blin[0];
    }
}

extern "C" void kernel_launch(void* const* d_in, const int* in_sizes, int n_in,
                              void* d_out, int out_size, void* d_ws, size_t ws_size,
                              hipStream_t stream)
{
    const float* x    = (const float*)d_in[0];
    const float* Wih0 = (const float*)d_in[1];
    const float* Whh0 = (const float*)d_in[2];
    const float* bih0 = (const float*)d_in[3];
    const float* bhh0 = (const float*)d_in[4];
    const float* Wih1 = (const float*)d_in[5];
    const float* Whh1 = (const float*)d_in[6];
    const float* bih1 = (const float*)d_in[7];
    const float* bhh1 = (const float*)d_in[8];
    const float* Wlin = (const float*)d_in[9];
    const float* blin = (const float*)d_in[10];
    int4* ws = (int4*)d_ws;   // requires ws_size >= 458,752 B

    hipLaunchKernelGGL(pack_w, dim3(F_TOTAL/256), dim3(256), 0, stream,
                       Wih0, Whh0, Wih1, Whh1, ws);
    hipLaunchKernelGGL(lstm_mfma, dim3(NB), dim3(512), 0, stream,
                       x, bih0, bhh0, bih1, bhh1, Wlin, blin, ws, (float*)d_out);
}